// Round 3
// baseline (3092.938 us; speedup 1.0000x reference)
//
#include <hip/hip_runtime.h>
#include <cstdint>

// ============================================================================
// TripleAdaptiveQuantizerV5 — round 3: block-per-m LDS mini-GEMM for the MLP.
//
// R1/R2 post-mortem: compiler keeps 64-float activation arrays in scratch
// (VGPR~100 both rounds, VALUBusy 15-21%) regardless of tiling -> latency-
// bound on scratch. R3 removes the dependence on SROA entirely: activations
// and weights live in LDS (by construction), each thread computes a 4x4
// (k,j) tile with 16 register accumulators. One m per 256-thread block;
// selection phase (threefry/gumbel/margin/f64-fallback) runs on wave 0 with
// lane=k, verbatim from the passing rounds. Every output neuron is still an
// i-ascending f32 FMA chain -> fast-path logits bit-identical to R1.
// ============================================================================

#define JAX_PARTITIONABLE 1

constexpr int BL = 64 * 256;  // 16384 (B*L)

// Output offsets (floats)
constexpr long long O_vq  = 0;
constexpr long long O_Hq  = 2097152;
constexpr long long O_yq  = 18874368;
constexpr long long O_eb  = 19136512;
constexpr long long O_wy  = 20185088;
constexpr long long O_wH  = 20283392;
constexpr long long O_wd  = 26574848;
constexpr long long O_yba = 32866304;
constexpr long long O_Hbl = 32882688;
constexpr long long O_dbl = 33931264;

#define MARGIN_THETA 3e-4

// ---------------------------------------------------------------- threefry
__device__ __forceinline__ uint32_t rotl32(uint32_t v, int d) {
  return (v << d) | (v >> (32 - d));
}

__device__ __forceinline__ void threefry2x32(uint32_t k0, uint32_t k1,
                                             uint32_t x0, uint32_t x1,
                                             uint32_t& o0, uint32_t& o1) {
  const uint32_t ks2 = k0 ^ k1 ^ 0x1BD11BDAu;
  x0 += k0; x1 += k1;
  x0 += x1; x1 = rotl32(x1, 13); x1 ^= x0;
  x0 += x1; x1 = rotl32(x1, 15); x1 ^= x0;
  x0 += x1; x1 = rotl32(x1, 26); x1 ^= x0;
  x0 += x1; x1 = rotl32(x1, 6);  x1 ^= x0;
  x0 += k1; x1 += ks2 + 1u;
  x0 += x1; x1 = rotl32(x1, 17); x1 ^= x0;
  x0 += x1; x1 = rotl32(x1, 29); x1 ^= x0;
  x0 += x1; x1 = rotl32(x1, 16); x1 ^= x0;
  x0 += x1; x1 = rotl32(x1, 24); x1 ^= x0;
  x0 += ks2; x1 += k0 + 2u;
  x0 += x1; x1 = rotl32(x1, 13); x1 ^= x0;
  x0 += x1; x1 = rotl32(x1, 15); x1 ^= x0;
  x0 += x1; x1 = rotl32(x1, 26); x1 ^= x0;
  x0 += x1; x1 = rotl32(x1, 6);  x1 ^= x0;
  x0 += k0; x1 += k1 + 3u;
  x0 += x1; x1 = rotl32(x1, 17); x1 ^= x0;
  x0 += x1; x1 = rotl32(x1, 29); x1 ^= x0;
  x0 += x1; x1 = rotl32(x1, 16); x1 ^= x0;
  x0 += x1; x1 = rotl32(x1, 24); x1 ^= x0;
  x0 += k1; x1 += ks2 + 4u;
  x0 += x1; x1 = rotl32(x1, 13); x1 ^= x0;
  x0 += x1; x1 = rotl32(x1, 15); x1 ^= x0;
  x0 += x1; x1 = rotl32(x1, 26); x1 ^= x0;
  x0 += x1; x1 = rotl32(x1, 6);  x1 ^= x0;
  x0 += ks2; x1 += k0 + 5u;
  o0 = x0; o1 = x1;
}

__device__ __forceinline__ uint32_t jax_randbits(uint32_t k0, uint32_t k1,
                                                 uint32_t e, uint32_t size) {
#if JAX_PARTITIONABLE
  (void)size;
  uint32_t o0, o1;
  threefry2x32(k0, k1, 0u, e, o0, o1);
  return o0 ^ o1;
#else
  const uint32_t half = size >> 1;
  uint32_t o0, o1;
  if (e < half) { threefry2x32(k0, k1, e, e + half, o0, o1); return o0; }
  threefry2x32(k0, k1, e - half, e, o0, o1); return o1;
#endif
}

// exact f32 replication of jax.random.uniform(minval=1e-10, maxval=1.0)
__device__ __forceinline__ float bits_to_unif(uint32_t bits) {
  float f = __uint_as_float((bits >> 9) | 0x3f800000u) - 1.0f;
  return fmaxf(1e-10f, f + 1e-10f);
}

// ---------------------------------------------------------------- helpers
__device__ __forceinline__ double wave_sum_f64(double x) {
#pragma unroll
  for (int off = 32; off > 0; off >>= 1) x += __shfl_xor(x, off);
  return x;
}

__device__ __forceinline__ void argmax_gap6(const double* s, int& arg, double& gap) {
  int a = 0;
#pragma unroll
  for (int j = 1; j < 6; ++j) if (s[j] > s[a]) a = j;
  double second = -1e300;
#pragma unroll
  for (int j = 0; j < 6; ++j) if (j != a && s[j] > second) second = s[j];
  arg = a; gap = s[a] - second;
}

__device__ __forceinline__ float idx_to_bits(int i) {
  return (float)((i < 4) ? 2 * (i + 1) : (i == 4 ? 12 : 16));
}

// rare-path f64 MLP (reads weights from global; rolled; __noinline__)
__device__ __noinline__ void mlp_f64_fallback(
    int m, int k, const float* __restrict__ v, const float* __restrict__ snr,
    double hp, double tp, double yp, double hpm,
    const float* __restrict__ w1, const float* __restrict__ b1,
    const float* __restrict__ w2, const float* __restrict__ b2,
    const float* __restrict__ w3, const float* __restrict__ b3,
    const float* __restrict__ wy, const float* __restrict__ by,
    const float* __restrict__ wh, const float* __restrict__ bh,
    const float* __restrict__ wd, const float* __restrict__ bd,
    double* __restrict__ ly, double* __restrict__ lh, double* __restrict__ ld) {
  const float2 vv = ((const float2*)v)[m * 64 + k];
  const float snrv = snr[m * 64 + k];
  double feat[9];
  feat[0] = (double)vv.x;
  feat[1] = (double)vv.y;
  feat[2] = (double)snrv;
  feat[3] = hp;
  feat[4] = hpm;
  feat[5] = log1p(hp / ((tp - hp) + 1e-10));
  feat[6] = log1p(tp);
  feat[7] = log1p(yp);
  feat[8] = sqrt(fma((double)vv.x, (double)vv.x,
                     fma((double)vv.y, (double)vv.y, 1e-10)));
  double h1[64], h2[64], h3[64];
#pragma unroll 1
  for (int j = 0; j < 64; ++j) {
    double a = (double)b1[j];
#pragma unroll 1
    for (int i = 0; i < 9; ++i) a = fma(feat[i], (double)w1[j * 9 + i], a);
    h1[j] = a > 0.0 ? a : 0.0;
  }
#pragma unroll 1
  for (int j = 0; j < 64; ++j) {
    double a = (double)b2[j];
#pragma unroll 1
    for (int i = 0; i < 64; ++i) a = fma(h1[i], (double)w2[j * 64 + i], a);
    h2[j] = a > 0.0 ? a : 0.0;
  }
#pragma unroll 1
  for (int j = 0; j < 64; ++j) {
    double a = (double)b3[j];
#pragma unroll 1
    for (int i = 0; i < 64; ++i) a = fma(h2[i], (double)w3[j * 64 + i], a);
    h3[j] = a > 0.0 ? a : 0.0;
  }
#pragma unroll 1
  for (int r = 0; r < 6; ++r) {
    double a = (double)by[r], c = (double)bh[r], d = (double)bd[r];
#pragma unroll 1
    for (int i = 0; i < 64; ++i) {
      const double x = h3[i];
      a = fma(x, (double)wy[r * 64 + i], a);
      c = fma(x, (double)wh[r * 64 + i], c);
      d = fma(x, (double)wd[r * 64 + i], d);
    }
    ly[r] = a; lh[r] = c; ld[r] = d;
  }
}

// ---------------------------------------------------------------- K0: ss + keys
__global__ void k0_setup(const float* __restrict__ sy, const float* __restrict__ sH,
                         const float* __restrict__ sd, float* __restrict__ ss,
                         uint32_t* __restrict__ keys) {
  const int t = threadIdx.x;
  if (t < 18) {
    const int tensor = t / 6, i = t % 6;
    const int qp_[6] = {1, 7, 31, 127, 2047, 32767};
    const long long sizes[3] = {262144LL, 16777216LL, 2097152LL};  // y, H, v
    const float* sarr = tensor == 0 ? sy : (tensor == 1 ? sH : sd);
    const double g64 = 1.0 / sqrt((double)(sizes[tensor] * (long long)qp_[i]));
    const float g32 = (float)g64;
    const float s = sarr[i];
    const float t1 = s * g32;
    ss[t] = t1 + (s - t1);  // _grad_scale forward, exact f32 sequence
  }
#if JAX_PARTITIONABLE
  if (t >= 32 && t < 35) {
    uint32_t o0, o1;
    threefry2x32(0u, 42u, 0u, (uint32_t)(t - 32), o0, o1);
    keys[(t - 32) * 2 + 0] = o0;
    keys[(t - 32) * 2 + 1] = o1;
  }
#else
  if (t == 32) {
    uint32_t a0, b0, a1, b1, a2, b2;
    threefry2x32(0u, 42u, 0u, 3u, a0, b0);
    threefry2x32(0u, 42u, 1u, 4u, a1, b1);
    threefry2x32(0u, 42u, 2u, 5u, a2, b2);
    keys[0] = a0; keys[1] = a1;
    keys[2] = a2; keys[3] = b0;
    keys[4] = b1; keys[5] = b2;
  }
#endif
}

// ---------------------------------------------------------------- K1: hp_mean
__global__ __launch_bounds__(128) void k1a_hpower_partial(
    const float* __restrict__ Hm, double* __restrict__ partial) {
  const int blk = blockIdx.x;       // 512 = 64 b * 8 l-chunks
  const int b = blk >> 3, lc = blk & 7;
  const int t = threadIdx.x;        // 128 = (k,c)
  const float* base = Hm + (size_t)(b * 256 + lc * 32) * 1024;
  double acc = 0.0;
  for (int l = 0; l < 32; ++l) {
#pragma unroll
    for (int n = 0; n < 8; ++n) {
      const float x = base[(size_t)l * 1024 + n * 128 + t];
      acc = fma((double)x, (double)x, acc);
    }
  }
  const double other = __shfl_xor(acc, 1);
  if ((t & 1) == 0) partial[(size_t)blk * 64 + (t >> 1)] = acc + other;
}

__global__ void k1b_hpmean(const double* __restrict__ partial,
                           double* __restrict__ hp_mean) {
  const int id = blockIdx.x * blockDim.x + threadIdx.x;  // 4096 = b*64+k
  if (id >= 4096) return;
  const int b = id >> 6, k = id & 63;
  double s = 0.0;
#pragma unroll
  for (int lc = 0; lc < 8; ++lc) s += partial[(size_t)(b * 8 + lc) * 64 + k];
  hp_mean[id] = s * (1.0 / 256.0);
}

// ---------------------------------------------------------------- GEMM tile
// out[k][j] = act(bias[j] + sum_i in[k][i]*W[j][i]); 256 thr = 16x16 tiles of
// 4x4. inT: LDS [i][k] stride 68; WT: LDS [i][j] stride 64 (transposed).
template <int NI, bool RELU>
__device__ __forceinline__ void gemm64(const float* __restrict__ inT,
                                       const float* __restrict__ WT,
                                       const float* __restrict__ bias,
                                       float* __restrict__ outT, int t) {
  const int k0 = (t & 15) * 4;
  const int j0 = (t >> 4) * 4;
  float acc[16];
#pragma unroll
  for (int jj = 0; jj < 4; ++jj) {
    const float bj = bias[j0 + jj];
#pragma unroll
    for (int kk = 0; kk < 4; ++kk) acc[jj * 4 + kk] = bj;
  }
#pragma unroll 16
  for (int i = 0; i < NI; ++i) {
    const float4 x  = *(const float4*)&inT[i * 68 + k0];
    const float4 wv = *(const float4*)&WT[i * 64 + j0];
    acc[0]  = fmaf(wv.x, x.x, acc[0]);
    acc[1]  = fmaf(wv.x, x.y, acc[1]);
    acc[2]  = fmaf(wv.x, x.z, acc[2]);
    acc[3]  = fmaf(wv.x, x.w, acc[3]);
    acc[4]  = fmaf(wv.y, x.x, acc[4]);
    acc[5]  = fmaf(wv.y, x.y, acc[5]);
    acc[6]  = fmaf(wv.y, x.z, acc[6]);
    acc[7]  = fmaf(wv.y, x.w, acc[7]);
    acc[8]  = fmaf(wv.z, x.x, acc[8]);
    acc[9]  = fmaf(wv.z, x.y, acc[9]);
    acc[10] = fmaf(wv.z, x.z, acc[10]);
    acc[11] = fmaf(wv.z, x.w, acc[11]);
    acc[12] = fmaf(wv.w, x.x, acc[12]);
    acc[13] = fmaf(wv.w, x.y, acc[13]);
    acc[14] = fmaf(wv.w, x.z, acc[14]);
    acc[15] = fmaf(wv.w, x.w, acc[15]);
  }
#pragma unroll
  for (int jj = 0; jj < 4; ++jj) {
    float4 r;
    r.x = acc[jj * 4 + 0];
    r.y = acc[jj * 4 + 1];
    r.z = acc[jj * 4 + 2];
    r.w = acc[jj * 4 + 3];
    if (RELU) {
      r.x = fmaxf(r.x, 0.0f); r.y = fmaxf(r.y, 0.0f);
      r.z = fmaxf(r.z, 0.0f); r.w = fmaxf(r.w, 0.0f);
    }
    *(float4*)&outT[(j0 + jj) * 68 + k0] = r;
  }
}

// heads: 18 rows (padded to 20), split 5/5/4/4 across the 4 waves; lane = k.
__device__ __forceinline__ void heads20(const float* __restrict__ actT,
                                        const float* __restrict__ whT,
                                        const float* __restrict__ by,
                                        const float* __restrict__ bh,
                                        const float* __restrict__ bd,
                                        float* __restrict__ headOut, int t) {
  const int k = t & 63, w = t >> 6;
  float acc[5];
#pragma unroll
  for (int q = 0; q < 5; ++q) {
    const int r = w + 4 * q;
    acc[q] = (r < 6) ? by[r] : (r < 12) ? bh[r - 6] : (r < 18) ? bd[r - 12] : 0.0f;
  }
#pragma unroll 8
  for (int i = 0; i < 64; ++i) {
    const float x = actT[i * 68 + k];
#pragma unroll
    for (int q = 0; q < 5; ++q)
      acc[q] = fmaf(x, whT[(w + 4 * q) * 64 + i], acc[q]);
  }
#pragma unroll
  for (int q = 0; q < 5; ++q) {
    const int r = w + 4 * q;
    if (r < 18) headOut[k * 20 + r] = acc[q];
  }
}

// ---------------------------------------------------------------- K2: main
// one m per 256-thread block; grid = 16384.
__global__ __launch_bounds__(256, 2) void k2_main(
    const float* __restrict__ v, const float* __restrict__ Hm,
    const float* __restrict__ y, const float* __restrict__ snr,
    const float* __restrict__ w1, const float* __restrict__ b1,
    const float* __restrict__ w2, const float* __restrict__ b2,
    const float* __restrict__ w3, const float* __restrict__ b3,
    const float* __restrict__ wy, const float* __restrict__ by,
    const float* __restrict__ wh, const float* __restrict__ bh,
    const float* __restrict__ wd, const float* __restrict__ bd,
    const double* __restrict__ hp_mean, const uint32_t* __restrict__ keys,
    float* __restrict__ out) {
  const int t = threadIdx.x;
  const int m = blockIdx.x;
  const int lane = t & 63;
  const int wv = t >> 6;

  // LDS carve-out: 18752 floats = 73.25 KB -> 2 blocks/CU
  __shared__ __align__(16) float smem[18752];
  float* w1T  = smem;           // 576   [i<9][j]
  float* w2T  = smem + 576;     // 4096  [i][j]
  float* w3T  = smem + 4672;    // 4096  [i][j]
  float* whT  = smem + 8768;    // 1280  [r<20][i]
  float* actA = smem + 10048;   // 4352  [row][k], stride 68
  float* actB = smem + 14400;   // 4352
  double* hp4 = (double*)actB;  // phase-A alias (consumed before L1 writes)
  float* headOut = actA;        // phase-C alias (actA free after L3)

  // ---- stage weights (transposed) ----
  for (int idx = t; idx < 576; idx += 256) {
    const int i = idx >> 6, j = idx & 63;
    w1T[idx] = w1[j * 9 + i];
  }
  for (int idx = t; idx < 4096; idx += 256) {
    const int i = idx >> 6, j = idx & 63;
    w2T[idx] = w2[j * 64 + i];
    w3T[idx] = w3[j * 64 + i];
  }
  for (int idx = t; idx < 1280; idx += 256) {
    const int r = idx >> 6, i = idx & 63;
    whT[idx] = (r < 6) ? wy[r * 64 + i]
             : (r < 12) ? wh[(r - 6) * 64 + i]
             : (r < 18) ? wd[(r - 12) * 64 + i] : 0.0f;
  }

  // ---- h_power partials: wave wv handles n in {2wv, 2wv+1} ----
  {
    const float2* Hp = (const float2*)Hm + (size_t)m * 512;
    double acc = 0.0;
#pragma unroll
    for (int nn = 0; nn < 2; ++nn) {
      const float2 h2v = Hp[(2 * wv + nn) * 64 + lane];
      acc = fma((double)h2v.x, (double)h2v.x, acc);
      acc = fma((double)h2v.y, (double)h2v.y, acc);
    }
    hp4[wv * 64 + lane] = acc;
  }
  __syncthreads();

  // ---- wave 0: finish features, write f32 feat rows into actA ----
  double hp = 0.0, tp = 0.0, yp = 0.0, hpm = 0.0;
  float2 vv = make_float2(0.0f, 0.0f);
  if (t < 64) {
    hp = hp4[lane] + hp4[64 + lane] + hp4[128 + lane] + hp4[192 + lane];
    tp = wave_sum_f64(hp);
    double ypart = 0.0;
    if (lane < 16) { const double yv = (double)y[m * 16 + lane]; ypart = yv * yv; }
    yp = wave_sum_f64(ypart);
    vv = ((const float2*)v)[m * 64 + lane];
    const float snrv = snr[m * 64 + lane];
    hpm = hp_mean[(m >> 8) * 64 + lane];
    float f[9];
    f[0] = (float)vv.x;
    f[1] = (float)vv.y;
    f[2] = snrv;
    f[3] = (float)hp;
    f[4] = (float)hpm;
    f[5] = (float)log1p(hp / ((tp - hp) + 1e-10));
    f[6] = (float)log1p(tp);
    f[7] = (float)log1p(yp);
    f[8] = (float)sqrt(fma((double)vv.x, (double)vv.x,
                           fma((double)vv.y, (double)vv.y, 1e-10)));
#pragma unroll
    for (int i = 0; i < 9; ++i) actA[i * 68 + lane] = f[i];
  }
  __syncthreads();

  // ---- MLP: 3 layers + heads, ping-pong actA/actB ----
  gemm64<9, true>(actA, w1T, b1, actB, t);
  __syncthreads();
  gemm64<64, true>(actB, w2T, b2, actA, t);
  __syncthreads();
  gemm64<64, true>(actA, w3T, b3, actB, t);
  __syncthreads();
  heads20(actB, whT, by, bh, bd, headOut, t);
  __syncthreads();

  if (t >= 64) return;  // waves 1-3 done; no further barriers

  // ---- phase C: selection on wave 0, lane = k (verbatim from R1/R2) ----
  const int k = lane;
  float ly[6], lh[6], ld[6];
#pragma unroll
  for (int j = 0; j < 6; ++j) {
    ly[j] = headOut[k * 20 + j];
    lh[j] = headOut[k * 20 + 6 + j];
    ld[j] = headOut[k * 20 + 12 + j];
  }

  const uint32_t g1k0 = keys[0], g1k1 = keys[1];
  const uint32_t g2k0 = keys[2], g2k1 = keys[3];
  const uint32_t g3k0 = keys[4], g3k1 = keys[5];

  float uHv[6], uDv[6];
  double sH[6], sD[6];
  const uint32_t eH = (uint32_t)(m * 64 + k) * 6u;
#pragma unroll
  for (int j = 0; j < 6; ++j) {
    const float u = bits_to_unif(jax_randbits(g2k0, g2k1, eH + j, 6291456u));
    uHv[j] = u;
    sH[j] = (double)lh[j] + (double)(-logf(-logf(u)));
  }
#pragma unroll
  for (int j = 0; j < 6; ++j) {
    const float u = bits_to_unif(jax_randbits(g3k0, g3k1, eH + j, 6291456u));
    uDv[j] = u;
    sD[j] = (double)ld[j] + (double)(-logf(-logf(u)));
  }
  int argH, argD; double gapH, gapD;
  argmax_gap6(sH, argH, gapH);
  argmax_gap6(sD, argD, gapD);

  double lysum[6];
#pragma unroll
  for (int j = 0; j < 6; ++j) lysum[j] = wave_sum_f64((double)ly[j]);

  int argY = 0; double gapY = 1e30;
  float uYv[6];
  if (k == 0) {
    double sY[6];
#pragma unroll
    for (int j = 0; j < 6; ++j) {
      const float u = bits_to_unif(jax_randbits(g1k0, g1k1, (uint32_t)(m * 6 + j), 98304u));
      uYv[j] = u;
      sY[j] = lysum[j] * (1.0 / 64.0) - log(-log((double)u));
    }
    argmax_gap6(sY, argY, gapY);
  }
  const int needY = __shfl((k == 0 && gapY < MARGIN_THETA) ? 1 : 0, 0);
  const bool needHD = (gapH < MARGIN_THETA) || (gapD < MARGIN_THETA);

  if (needHD || needY) {  // rare: full f64 recompute
    double lyd[6], lhd[6], ldd[6];
    mlp_f64_fallback(m, k, v, snr, hp, tp, yp, hpm,
                     w1, b1, w2, b2, w3, b3, wy, by, wh, bh, wd, bd,
                     lyd, lhd, ldd);
    if (gapH < MARGIN_THETA) {
      double s2[6];
#pragma unroll
      for (int j = 0; j < 6; ++j) s2[j] = lhd[j] - log(-log((double)uHv[j]));
      double g; argmax_gap6(s2, argH, g);
    }
    if (gapD < MARGIN_THETA) {
      double s2[6];
#pragma unroll
      for (int j = 0; j < 6; ++j) s2[j] = ldd[j] - log(-log((double)uDv[j]));
      double g; argmax_gap6(s2, argD, g);
    }
    if (needY) {  // wave-uniform predicate over wave 0
      double lys2[6];
#pragma unroll
      for (int j = 0; j < 6; ++j) lys2[j] = wave_sum_f64(lyd[j]);
      if (k == 0) {
        double s2[6];
#pragma unroll
        for (int j = 0; j < 6; ++j)
          s2[j] = lys2[j] * (1.0 / 64.0) - log(-log((double)uYv[j]));
        double g; argmax_gap6(s2, argY, g);
      }
    }
  }
  argY = __shfl(argY, 0);

  // ---- outputs ----
  const float bY = 16.0f * idx_to_bits(argY);   // 2*N*bits
  const float bH = 16.0f * idx_to_bits(argH);
  const float bD = 2.0f * idx_to_bits(argD);

  if (k == 0) {
    out[O_yba + m] = bY;
#pragma unroll
    for (int j = 0; j < 6; ++j) out[O_wy + m * 6 + j] = (j == argY) ? 1.0f : 0.0f;
  }
  out[O_Hbl + (size_t)m * 64 + k] = bH;
  out[O_dbl + (size_t)m * 64 + k] = bD;
  out[O_eb + (size_t)m * 64 + k] = (bY * 0.015625f + bH) + bD;
#pragma unroll
  for (int j = 0; j < 6; ++j) {
    out[O_wH + (size_t)(m * 64 + k) * 6 + j] = (j == argH) ? 1.0f : 0.0f;
    out[O_wd + (size_t)(m * 64 + k) * 6 + j] = (j == argD) ? 1.0f : 0.0f;
  }
}

// ---------------------------------------------------------------- LSQ quant
__device__ __forceinline__ int bits_to_idx(int bits) {
  return (bits <= 8) ? ((bits >> 1) - 1) : ((bits == 12) ? 4 : 5);
}

__device__ __forceinline__ float lsq1(float x, float ssv, float qn, float qp) {
  float t = x / ssv;
  t = fminf(fmaxf(t, qn), qp);
  return rintf(t) * ssv;
}

__global__ void k3_Hq(const float* __restrict__ Hm, const float* __restrict__ ss,
                      const float* __restrict__ Hbits, float* __restrict__ outHq) {
  const int id = blockIdx.x * blockDim.x + threadIdx.x;
  if (id >= 8388608) return;
  const int k = id & 63;
  const int m = id >> 9;
  const int bits = (int)Hbits[(size_t)m * 64 + k] >> 4;
  const int i = bits_to_idx(bits);
  const float ssv = ss[6 + i];
  const float qp = (float)((1 << (bits - 1)) - 1);
  const float qn = -(float)(1 << (bits - 1));
  const float2 x = ((const float2*)Hm)[id];
  float2 o;
  o.x = lsq1(x.x, ssv, qn, qp);
  o.y = lsq1(x.y, ssv, qn, qp);
  ((float2*)outHq)[id] = o;
}

__global__ void k4_vq(const float* __restrict__ v, const float* __restrict__ ss,
                      const float* __restrict__ dbits, float* __restrict__ outvq) {
  const int id = blockIdx.x * blockDim.x + threadIdx.x;
  if (id >= 1048576) return;
  const int bits = (int)dbits[id] >> 1;
  const int i = bits_to_idx(bits);
  const float ssv = ss[12 + i];
  const float qp = (float)((1 << (bits - 1)) - 1);
  const float qn = -(float)(1 << (bits - 1));
  const float2 x = ((const float2*)v)[id];
  float2 o;
  o.x = lsq1(x.x, ssv, qn, qp);
  o.y = lsq1(x.y, ssv, qn, qp);
  ((float2*)outvq)[id] = o;
}

__global__ void k5_yq(const float* __restrict__ y, const float* __restrict__ ss,
                      const float* __restrict__ ybits, float* __restrict__ outyq) {
  const int id = blockIdx.x * blockDim.x + threadIdx.x;
  if (id >= 131072) return;
  const int m = id >> 3;
  const int bits = (int)ybits[m] >> 4;
  const int i = bits_to_idx(bits);
  const float ssv = ss[i];
  const float qp = (float)((1 << (bits - 1)) - 1);
  const float qn = -(float)(1 << (bits - 1));
  const float2 x = ((const float2*)y)[id];
  float2 o;
  o.x = lsq1(x.x, ssv, qn, qp);
  o.y = lsq1(x.y, ssv, qn, qp);
  ((float2*)outyq)[id] = o;
}

// ---------------------------------------------------------------- launch
extern "C" void kernel_launch(void* const* d_in, const int* in_sizes, int n_in,
                              void* d_out, int out_size, void* d_ws, size_t ws_size,
                              hipStream_t stream) {
  const float* v   = (const float*)d_in[0];
  const float* Hm  = (const float*)d_in[1];
  const float* y   = (const float*)d_in[2];
  const float* snr = (const float*)d_in[3];
  const float* w1  = (const float*)d_in[4];
  const float* b1  = (const float*)d_in[5];
  const float* w2  = (const float*)d_in[6];
  const float* b2  = (const float*)d_in[7];
  const float* w3  = (const float*)d_in[8];
  const float* b3  = (const float*)d_in[9];
  const float* wy  = (const float*)d_in[10];
  const float* by  = (const float*)d_in[11];
  const float* wh  = (const float*)d_in[12];
  const float* bh  = (const float*)d_in[13];
  const float* wd  = (const float*)d_in[14];
  const float* bd  = (const float*)d_in[15];
  const float* sy  = (const float*)d_in[16];
  const float* sH  = (const float*)d_in[17];
  const float* sd  = (const float*)d_in[18];

  float* out = (float*)d_out;

  double* ws_partial = (double*)d_ws;
  double* ws_hpmean  = ws_partial + 32768;
  float*  ws_ss      = (float*)(ws_hpmean + 4096);
  uint32_t* ws_keys  = (uint32_t*)(ws_ss + 18);

  k0_setup<<<1, 64, 0, stream>>>(sy, sH, sd, ws_ss, ws_keys);
  k1a_hpower_partial<<<512, 128, 0, stream>>>(Hm, ws_partial);
  k1b_hpmean<<<16, 256, 0, stream>>>(ws_partial, ws_hpmean);
  k2_main<<<BL, 256, 0, stream>>>(v, Hm, y, snr, w1, b1, w2, b2, w3, b3,
                                  wy, by, wh, bh, wd, bd, ws_hpmean, ws_keys, out);
  k3_Hq<<<32768, 256, 0, stream>>>(Hm, ws_ss, out + O_Hbl, out + O_Hq);
  k4_vq<<<4096, 256, 0, stream>>>(v, ws_ss, out + O_dbl, out + O_vq);
  k5_yq<<<512, 256, 0, stream>>>(y, ws_ss, out + O_yba, out + O_yq);
}

// Round 4
// 1824.945 us; speedup vs baseline: 1.6948x; 1.6948x over previous
//
#include <hip/hip_runtime.h>
#include <cstdint>

// ============================================================================
// TripleAdaptiveQuantizerV5 — round 4: parallel phase C + exiled f64 fallback.
//
// R3 post-mortem: Occupancy 6.7% = 2 blocks x 1 wave -> block lifetime was
// the single-wave selection tail + the inline f64 fallback (rolled loop with
// a dependent global load per f64 FMA, ~1M+ cyc per trip, ~4% of waves).
// R4: (a) 4 m per block, weights staged once, each wave owns one m's
// selection -> no single-wave tail; (b) fallback moved to kernel kfix:
// hot kernel writes flag bytes into the v_q output region (k4 overwrites it
// later), kfix refines flagged samples with the bit-exact f64 path and
// rewrites affected outputs. All numeric sequences verbatim from R3 (passing).
// ============================================================================

#define JAX_PARTITIONABLE 1

constexpr int BL = 64 * 256;  // 16384 (B*L)

// Output offsets (floats)
constexpr long long O_vq  = 0;
constexpr long long O_Hq  = 2097152;
constexpr long long O_yq  = 18874368;
constexpr long long O_eb  = 19136512;
constexpr long long O_wy  = 20185088;
constexpr long long O_wH  = 20283392;
constexpr long long O_wd  = 26574848;
constexpr long long O_yba = 32866304;
constexpr long long O_Hbl = 32882688;
constexpr long long O_dbl = 33931264;

// flag stash inside the v_q region (k4 overwrites all of v_q afterwards)
constexpr long long F_SAMPLE = 0;        // 1048576 bytes, 1 per (m,k)
constexpr long long F_M      = 1048576;  // 16384 bytes, 1 per m

#define MARGIN_THETA 3e-4

// ---------------------------------------------------------------- threefry
__device__ __forceinline__ uint32_t rotl32(uint32_t v, int d) {
  return (v << d) | (v >> (32 - d));
}

__device__ __forceinline__ void threefry2x32(uint32_t k0, uint32_t k1,
                                             uint32_t x0, uint32_t x1,
                                             uint32_t& o0, uint32_t& o1) {
  const uint32_t ks2 = k0 ^ k1 ^ 0x1BD11BDAu;
  x0 += k0; x1 += k1;
  x0 += x1; x1 = rotl32(x1, 13); x1 ^= x0;
  x0 += x1; x1 = rotl32(x1, 15); x1 ^= x0;
  x0 += x1; x1 = rotl32(x1, 26); x1 ^= x0;
  x0 += x1; x1 = rotl32(x1, 6);  x1 ^= x0;
  x0 += k1; x1 += ks2 + 1u;
  x0 += x1; x1 = rotl32(x1, 17); x1 ^= x0;
  x0 += x1; x1 = rotl32(x1, 29); x1 ^= x0;
  x0 += x1; x1 = rotl32(x1, 16); x1 ^= x0;
  x0 += x1; x1 = rotl32(x1, 24); x1 ^= x0;
  x0 += ks2; x1 += k0 + 2u;
  x0 += x1; x1 = rotl32(x1, 13); x1 ^= x0;
  x0 += x1; x1 = rotl32(x1, 15); x1 ^= x0;
  x0 += x1; x1 = rotl32(x1, 26); x1 ^= x0;
  x0 += x1; x1 = rotl32(x1, 6);  x1 ^= x0;
  x0 += k0; x1 += k1 + 3u;
  x0 += x1; x1 = rotl32(x1, 17); x1 ^= x0;
  x0 += x1; x1 = rotl32(x1, 29); x1 ^= x0;
  x0 += x1; x1 = rotl32(x1, 16); x1 ^= x0;
  x0 += x1; x1 = rotl32(x1, 24); x1 ^= x0;
  x0 += k1; x1 += ks2 + 4u;
  x0 += x1; x1 = rotl32(x1, 13); x1 ^= x0;
  x0 += x1; x1 = rotl32(x1, 15); x1 ^= x0;
  x0 += x1; x1 = rotl32(x1, 26); x1 ^= x0;
  x0 += x1; x1 = rotl32(x1, 6);  x1 ^= x0;
  x0 += ks2; x1 += k0 + 5u;
  o0 = x0; o1 = x1;
}

__device__ __forceinline__ uint32_t jax_randbits(uint32_t k0, uint32_t k1,
                                                 uint32_t e, uint32_t size) {
#if JAX_PARTITIONABLE
  (void)size;
  uint32_t o0, o1;
  threefry2x32(k0, k1, 0u, e, o0, o1);
  return o0 ^ o1;
#else
  const uint32_t half = size >> 1;
  uint32_t o0, o1;
  if (e < half) { threefry2x32(k0, k1, e, e + half, o0, o1); return o0; }
  threefry2x32(k0, k1, e - half, e, o0, o1); return o1;
#endif
}

// exact f32 replication of jax.random.uniform(minval=1e-10, maxval=1.0)
__device__ __forceinline__ float bits_to_unif(uint32_t bits) {
  float f = __uint_as_float((bits >> 9) | 0x3f800000u) - 1.0f;
  return fmaxf(1e-10f, f + 1e-10f);
}

// ---------------------------------------------------------------- helpers
__device__ __forceinline__ double wave_sum_f64(double x) {
#pragma unroll
  for (int off = 32; off > 0; off >>= 1) x += __shfl_xor(x, off);
  return x;
}

__device__ __forceinline__ void argmax_gap6(const double* s, int& arg, double& gap) {
  int a = 0;
#pragma unroll
  for (int j = 1; j < 6; ++j) if (s[j] > s[a]) a = j;
  double second = -1e300;
#pragma unroll
  for (int j = 0; j < 6; ++j) if (j != a && s[j] > second) second = s[j];
  arg = a; gap = s[a] - second;
}

__device__ __forceinline__ float idx_to_bits(int i) {
  return (float)((i < 4) ? 2 * (i + 1) : (i == 4 ? 12 : 16));
}

// ---------------------------------------------------------------- K0: ss + keys
__global__ void k0_setup(const float* __restrict__ sy, const float* __restrict__ sH,
                         const float* __restrict__ sd, float* __restrict__ ss,
                         uint32_t* __restrict__ keys) {
  const int t = threadIdx.x;
  if (t < 18) {
    const int tensor = t / 6, i = t % 6;
    const int qp_[6] = {1, 7, 31, 127, 2047, 32767};
    const long long sizes[3] = {262144LL, 16777216LL, 2097152LL};  // y, H, v
    const float* sarr = tensor == 0 ? sy : (tensor == 1 ? sH : sd);
    const double g64 = 1.0 / sqrt((double)(sizes[tensor] * (long long)qp_[i]));
    const float g32 = (float)g64;
    const float s = sarr[i];
    const float t1 = s * g32;
    ss[t] = t1 + (s - t1);  // _grad_scale forward, exact f32 sequence
  }
#if JAX_PARTITIONABLE
  if (t >= 32 && t < 35) {
    uint32_t o0, o1;
    threefry2x32(0u, 42u, 0u, (uint32_t)(t - 32), o0, o1);
    keys[(t - 32) * 2 + 0] = o0;
    keys[(t - 32) * 2 + 1] = o1;
  }
#else
  if (t == 32) {
    uint32_t a0, b0, a1, b1, a2, b2;
    threefry2x32(0u, 42u, 0u, 3u, a0, b0);
    threefry2x32(0u, 42u, 1u, 4u, a1, b1);
    threefry2x32(0u, 42u, 2u, 5u, a2, b2);
    keys[0] = a0; keys[1] = a1;
    keys[2] = a2; keys[3] = b0;
    keys[4] = b1; keys[5] = b2;
  }
#endif
}

// ---------------------------------------------------------------- K1: hp_mean
__global__ __launch_bounds__(128) void k1a_hpower_partial(
    const float* __restrict__ Hm, double* __restrict__ partial) {
  const int blk = blockIdx.x;       // 512 = 64 b * 8 l-chunks
  const int b = blk >> 3, lc = blk & 7;
  const int t = threadIdx.x;        // 128 = (k,c)
  const float* base = Hm + (size_t)(b * 256 + lc * 32) * 1024;
  double acc = 0.0;
  for (int l = 0; l < 32; ++l) {
#pragma unroll
    for (int n = 0; n < 8; ++n) {
      const float x = base[(size_t)l * 1024 + n * 128 + t];
      acc = fma((double)x, (double)x, acc);
    }
  }
  const double other = __shfl_xor(acc, 1);
  if ((t & 1) == 0) partial[(size_t)blk * 64 + (t >> 1)] = acc + other;
}

__global__ void k1b_hpmean(const double* __restrict__ partial,
                           double* __restrict__ hp_mean) {
  const int id = blockIdx.x * blockDim.x + threadIdx.x;  // 4096 = b*64+k
  if (id >= 4096) return;
  const int b = id >> 6, k = id & 63;
  double s = 0.0;
#pragma unroll
  for (int lc = 0; lc < 8; ++lc) s += partial[(size_t)(b * 8 + lc) * 64 + k];
  hp_mean[id] = s * (1.0 / 256.0);
}

// ---------------------------------------------------------------- GEMM tile
// out[k][j] = act(bias[j] + sum_i in[k][i]*W[j][i]); 256 thr = 16x16 tiles of
// 4x4. inT: LDS [i][k] stride 68; WT: LDS [i][j] stride 64 (transposed).
template <int NI, bool RELU>
__device__ __forceinline__ void gemm64(const float* __restrict__ inT,
                                       const float* __restrict__ WT,
                                       const float* __restrict__ bias,
                                       float* __restrict__ outT, int t) {
  const int k0 = (t & 15) * 4;
  const int j0 = (t >> 4) * 4;
  float acc[16];
#pragma unroll
  for (int jj = 0; jj < 4; ++jj) {
    const float bj = bias[j0 + jj];
#pragma unroll
    for (int kk = 0; kk < 4; ++kk) acc[jj * 4 + kk] = bj;
  }
#pragma unroll 16
  for (int i = 0; i < NI; ++i) {
    const float4 x  = *(const float4*)&inT[i * 68 + k0];
    const float4 wv = *(const float4*)&WT[i * 64 + j0];
    acc[0]  = fmaf(wv.x, x.x, acc[0]);
    acc[1]  = fmaf(wv.x, x.y, acc[1]);
    acc[2]  = fmaf(wv.x, x.z, acc[2]);
    acc[3]  = fmaf(wv.x, x.w, acc[3]);
    acc[4]  = fmaf(wv.y, x.x, acc[4]);
    acc[5]  = fmaf(wv.y, x.y, acc[5]);
    acc[6]  = fmaf(wv.y, x.z, acc[6]);
    acc[7]  = fmaf(wv.y, x.w, acc[7]);
    acc[8]  = fmaf(wv.z, x.x, acc[8]);
    acc[9]  = fmaf(wv.z, x.y, acc[9]);
    acc[10] = fmaf(wv.z, x.z, acc[10]);
    acc[11] = fmaf(wv.z, x.w, acc[11]);
    acc[12] = fmaf(wv.w, x.x, acc[12]);
    acc[13] = fmaf(wv.w, x.y, acc[13]);
    acc[14] = fmaf(wv.w, x.z, acc[14]);
    acc[15] = fmaf(wv.w, x.w, acc[15]);
  }
#pragma unroll
  for (int jj = 0; jj < 4; ++jj) {
    float4 r;
    r.x = acc[jj * 4 + 0];
    r.y = acc[jj * 4 + 1];
    r.z = acc[jj * 4 + 2];
    r.w = acc[jj * 4 + 3];
    if (RELU) {
      r.x = fmaxf(r.x, 0.0f); r.y = fmaxf(r.y, 0.0f);
      r.z = fmaxf(r.z, 0.0f); r.w = fmaxf(r.w, 0.0f);
    }
    *(float4*)&outT[(j0 + jj) * 68 + k0] = r;
  }
}

// heads: 18 rows (padded to 20), split 5/5/4/4 across the 4 waves; lane = k.
__device__ __forceinline__ void heads20(const float* __restrict__ actT,
                                        const float* __restrict__ whT,
                                        const float* __restrict__ by,
                                        const float* __restrict__ bh,
                                        const float* __restrict__ bd,
                                        float* __restrict__ headP, int t) {
  const int k = t & 63, w = t >> 6;
  float acc[5];
#pragma unroll
  for (int q = 0; q < 5; ++q) {
    const int r = w + 4 * q;
    acc[q] = (r < 6) ? by[r] : (r < 12) ? bh[r - 6] : (r < 18) ? bd[r - 12] : 0.0f;
  }
#pragma unroll 8
  for (int i = 0; i < 64; ++i) {
    const float x = actT[i * 68 + k];
#pragma unroll
    for (int q = 0; q < 5; ++q)
      acc[q] = fmaf(x, whT[(w + 4 * q) * 64 + i], acc[q]);
  }
#pragma unroll
  for (int q = 0; q < 5; ++q) {
    const int r = w + 4 * q;
    if (r < 18) headP[k * 20 + r] = acc[q];
  }
}

// ---------------------------------------------------------------- K2: main
// 4 m per 256-thread block; grid = 4096. Each wave owns one m's selection.
__global__ __launch_bounds__(256, 2) void k2_main(
    const float* __restrict__ v, const float* __restrict__ Hm,
    const float* __restrict__ y, const float* __restrict__ snr,
    const float* __restrict__ w1, const float* __restrict__ b1,
    const float* __restrict__ w2, const float* __restrict__ b2,
    const float* __restrict__ w3, const float* __restrict__ b3,
    const float* __restrict__ wy, const float* __restrict__ by,
    const float* __restrict__ wh, const float* __restrict__ bh,
    const float* __restrict__ wd, const float* __restrict__ bd,
    const double* __restrict__ hp_mean, const uint32_t* __restrict__ keys,
    float* __restrict__ out) {
  const int t = threadIdx.x;
  const int lane = t & 63;
  const int wvx = t >> 6;
  const int m0 = blockIdx.x * 4;

  // LDS: 20032 floats = 78.25 KB -> 2 blocks/CU (160 KiB budget)
  __shared__ __align__(16) float smem[20032];
  float* w1T   = smem;           // 576   [i<9][j]
  float* w2T   = smem + 576;     // 4096  [i][j]
  float* w3T   = smem + 4672;    // 4096  [i][j]
  float* whT   = smem + 8768;    // 1280  [r<20][i]
  float* actA  = smem + 10048;   // 4352  [row][k], stride 68
  float* actB  = smem + 14400;   // 4352
  float* headP = smem + 18752;   // 1280  [k][20]
  double* hp4  = (double*)actB;  // per-mc alias (consumed before L1 writes)

  // ---- stage weights (transposed) once for 4 m ----
  for (int idx = t; idx < 576; idx += 256) {
    const int i = idx >> 6, j = idx & 63;
    w1T[idx] = w1[j * 9 + i];
  }
  for (int idx = t; idx < 4096; idx += 256) {
    const int i = idx >> 6, j = idx & 63;
    w2T[idx] = w2[j * 64 + i];
    w3T[idx] = w3[j * 64 + i];
  }
  for (int idx = t; idx < 1280; idx += 256) {
    const int r = idx >> 6, i = idx & 63;
    whT[idx] = (r < 6) ? wy[r * 64 + i]
             : (r < 12) ? wh[(r - 6) * 64 + i]
             : (r < 18) ? wd[(r - 12) * 64 + i] : 0.0f;
  }

  float ly[6], lh[6], ld[6];
#pragma unroll 1
  for (int mc = 0; mc < 4; ++mc) {
    const int m = m0 + mc;
    // hp partials: wave wvx handles n in {2wvx, 2wvx+1} (same split as R3)
    {
      const float2* Hp = (const float2*)Hm + (size_t)m * 512;
      double acc = 0.0;
#pragma unroll
      for (int nn = 0; nn < 2; ++nn) {
        const float2 h2v = Hp[(2 * wvx + nn) * 64 + lane];
        acc = fma((double)h2v.x, (double)h2v.x, acc);
        acc = fma((double)h2v.y, (double)h2v.y, acc);
      }
      __syncthreads();  // protect hp4 region (actB) from prior-phase readers
      hp4[wvx * 64 + lane] = acc;
    }
    __syncthreads();

    // wave mc finishes features for m and writes f32 rows into actA
    if (wvx == mc) {
      const double hp = ((hp4[lane] + hp4[64 + lane]) + hp4[128 + lane]) + hp4[192 + lane];
      const double tp = wave_sum_f64(hp);
      double ypart = 0.0;
      if (lane < 16) { const double yv = (double)y[m * 16 + lane]; ypart = yv * yv; }
      const double yp = wave_sum_f64(ypart);
      const float2 vv = ((const float2*)v)[m * 64 + lane];
      const float snrv = snr[m * 64 + lane];
      const double hpm = hp_mean[(m >> 8) * 64 + lane];
      float f[9];
      f[0] = (float)vv.x;
      f[1] = (float)vv.y;
      f[2] = snrv;
      f[3] = (float)hp;
      f[4] = (float)hpm;
      f[5] = (float)log1p(hp / ((tp - hp) + 1e-10));
      f[6] = (float)log1p(tp);
      f[7] = (float)log1p(yp);
      f[8] = (float)sqrt(fma((double)vv.x, (double)vv.x,
                             fma((double)vv.y, (double)vv.y, 1e-10)));
#pragma unroll
      for (int i = 0; i < 9; ++i) actA[i * 68 + lane] = f[i];
    }
    __syncthreads();

    gemm64<9, true>(actA, w1T, b1, actB, t);
    __syncthreads();
    gemm64<64, true>(actB, w2T, b2, actA, t);
    __syncthreads();
    gemm64<64, true>(actA, w3T, b3, actB, t);
    __syncthreads();
    heads20(actB, whT, by, bh, bd, headP, t);
    __syncthreads();

    if (wvx == mc) {  // stash this wave's m logits to registers
#pragma unroll
      for (int j = 0; j < 6; ++j) {
        ly[j] = headP[lane * 20 + j];
        lh[j] = headP[lane * 20 + 6 + j];
        ld[j] = headP[lane * 20 + 12 + j];
      }
    }
  }

  // ---- phase C: each wave handles its own m (verbatim R3 numerics) ----
  const int m = m0 + wvx;
  const int k = lane;

  const uint32_t g1k0 = keys[0], g1k1 = keys[1];
  const uint32_t g2k0 = keys[2], g2k1 = keys[3];
  const uint32_t g3k0 = keys[4], g3k1 = keys[5];

  double sH[6], sD[6];
  const uint32_t eH = (uint32_t)(m * 64 + k) * 6u;
#pragma unroll
  for (int j = 0; j < 6; ++j) {
    const float u = bits_to_unif(jax_randbits(g2k0, g2k1, eH + j, 6291456u));
    sH[j] = (double)lh[j] + (double)(-logf(-logf(u)));
  }
#pragma unroll
  for (int j = 0; j < 6; ++j) {
    const float u = bits_to_unif(jax_randbits(g3k0, g3k1, eH + j, 6291456u));
    sD[j] = (double)ld[j] + (double)(-logf(-logf(u)));
  }
  int argH, argD; double gapH, gapD;
  argmax_gap6(sH, argH, gapH);
  argmax_gap6(sD, argD, gapD);

  double lysum[6];
#pragma unroll
  for (int j = 0; j < 6; ++j) lysum[j] = wave_sum_f64((double)ly[j]);

  int argY = 0; double gapY = 1e30;
  if (k == 0) {
    double sY[6];
#pragma unroll
    for (int j = 0; j < 6; ++j) {
      const float u = bits_to_unif(jax_randbits(g1k0, g1k1, (uint32_t)(m * 6 + j), 98304u));
      sY[j] = lysum[j] * (1.0 / 64.0) - log(-log((double)u));
    }
    argmax_gap6(sY, argY, gapY);
  }
  const int needY = __shfl((k == 0 && gapY < MARGIN_THETA) ? 1 : 0, 0);
  const bool fH = gapH < MARGIN_THETA;
  const bool fD = gapD < MARGIN_THETA;

  // flags -> v_q region (k4 overwrites it later)
  uint8_t* flags = (uint8_t*)(out + O_vq);
  flags[F_SAMPLE + (size_t)m * 64 + k] = (uint8_t)((fH ? 1 : 0) | (fD ? 2 : 0));
  const bool anyHD = __ballot(fH || fD) != 0ull;
  if (k == 0)
    flags[F_M + m] = (uint8_t)(((anyHD || needY) ? 1 : 0) | (needY ? 2 : 0));

  argY = __shfl(argY, 0);

  // ---- provisional outputs (kfix overwrites flagged entries) ----
  const float bY = 16.0f * idx_to_bits(argY);   // 2*N*bits
  const float bH = 16.0f * idx_to_bits(argH);
  const float bD = 2.0f * idx_to_bits(argD);

  if (k == 0) {
    out[O_yba + m] = bY;
#pragma unroll
    for (int j = 0; j < 6; ++j) out[O_wy + m * 6 + j] = (j == argY) ? 1.0f : 0.0f;
  }
  out[O_Hbl + (size_t)m * 64 + k] = bH;
  out[O_dbl + (size_t)m * 64 + k] = bD;
  out[O_eb + (size_t)m * 64 + k] = (bY * 0.015625f + bH) + bD;
#pragma unroll
  for (int j = 0; j < 6; ++j) {
    out[O_wH + (size_t)(m * 64 + k) * 6 + j] = (j == argH) ? 1.0f : 0.0f;
    out[O_wd + (size_t)(m * 64 + k) * 6 + j] = (j == argD) ? 1.0f : 0.0f;
  }
}

// ---------------------------------------------------------------- kfix
// One 64-thread block per m; early-exit unless flagged. Recomputes the f64
// path bit-identically to R3's inline fallback and rewrites affected outputs.
__global__ __launch_bounds__(64) void kfix(
    const float* __restrict__ v, const float* __restrict__ Hm,
    const float* __restrict__ y, const float* __restrict__ snr,
    const float* __restrict__ w1, const float* __restrict__ b1,
    const float* __restrict__ w2, const float* __restrict__ b2,
    const float* __restrict__ w3, const float* __restrict__ b3,
    const float* __restrict__ wy, const float* __restrict__ by,
    const float* __restrict__ wh, const float* __restrict__ bh,
    const float* __restrict__ wd, const float* __restrict__ bd,
    const double* __restrict__ hp_mean, const uint32_t* __restrict__ keys,
    float* __restrict__ out) {
  const int m = blockIdx.x;
  const int k = threadIdx.x;
  const uint8_t* flags = (const uint8_t*)(out + O_vq);
  const uint8_t mf = flags[F_M + m];
  if (mf == 0) return;
  const uint8_t f = flags[F_SAMPLE + (size_t)m * 64 + k];

  // ---- recompute f64 features, bit-identical op order to the hot kernel ----
  const float2* Hp = (const float2*)Hm + (size_t)m * 512;
  double p[4];
#pragma unroll
  for (int w = 0; w < 4; ++w) {
    double acc = 0.0;
#pragma unroll
    for (int nn = 0; nn < 2; ++nn) {
      const float2 h2v = Hp[(2 * w + nn) * 64 + k];
      acc = fma((double)h2v.x, (double)h2v.x, acc);
      acc = fma((double)h2v.y, (double)h2v.y, acc);
    }
    p[w] = acc;
  }
  const double hp = ((p[0] + p[1]) + p[2]) + p[3];
  const double tp = wave_sum_f64(hp);
  double ypart = 0.0;
  if (k < 16) { const double yv = (double)y[m * 16 + k]; ypart = yv * yv; }
  const double yp = wave_sum_f64(ypart);
  const float2 vv = ((const float2*)v)[m * 64 + k];
  const float snrv = snr[m * 64 + k];
  const double hpm = hp_mean[(m >> 8) * 64 + k];

  double feat[9];
  feat[0] = (double)vv.x;
  feat[1] = (double)vv.y;
  feat[2] = (double)snrv;
  feat[3] = hp;
  feat[4] = hpm;
  feat[5] = log1p(hp / ((tp - hp) + 1e-10));
  feat[6] = log1p(tp);
  feat[7] = log1p(yp);
  feat[8] = sqrt(fma((double)vv.x, (double)vv.x,
                     fma((double)vv.y, (double)vv.y, 1e-10)));

  // ---- f64 MLP (verbatim structure from R3's verified fallback) ----
  double h1[64], h2[64], h3[64];
#pragma unroll 1
  for (int j = 0; j < 64; ++j) {
    double a = (double)b1[j];
#pragma unroll 1
    for (int i = 0; i < 9; ++i) a = fma(feat[i], (double)w1[j * 9 + i], a);
    h1[j] = a > 0.0 ? a : 0.0;
  }
#pragma unroll 1
  for (int j = 0; j < 64; ++j) {
    double a = (double)b2[j];
#pragma unroll 1
    for (int i = 0; i < 64; ++i) a = fma(h1[i], (double)w2[j * 64 + i], a);
    h2[j] = a > 0.0 ? a : 0.0;
  }
#pragma unroll 1
  for (int j = 0; j < 64; ++j) {
    double a = (double)b3[j];
#pragma unroll 1
    for (int i = 0; i < 64; ++i) a = fma(h2[i], (double)w3[j * 64 + i], a);
    h3[j] = a > 0.0 ? a : 0.0;
  }
  double lyd[6], lhd[6], ldd[6];
#pragma unroll 1
  for (int r = 0; r < 6; ++r) {
    double a = (double)by[r], c = (double)bh[r], d = (double)bd[r];
#pragma unroll 1
    for (int i = 0; i < 64; ++i) {
      const double x = h3[i];
      a = fma(x, (double)wy[r * 64 + i], a);
      c = fma(x, (double)wh[r * 64 + i], c);
      d = fma(x, (double)wd[r * 64 + i], d);
    }
    lyd[r] = a; lhd[r] = c; ldd[r] = d;
  }

  const uint32_t g1k0 = keys[0], g1k1 = keys[1];
  const uint32_t g2k0 = keys[2], g2k1 = keys[3];
  const uint32_t g3k0 = keys[4], g3k1 = keys[5];
  const uint32_t eH = (uint32_t)(m * 64 + k) * 6u;

  float bHf, bDf;
  if (f & 1) {
    double s2[6];
#pragma unroll
    for (int j = 0; j < 6; ++j) {
      const float u = bits_to_unif(jax_randbits(g2k0, g2k1, eH + j, 6291456u));
      s2[j] = lhd[j] - log(-log((double)u));
    }
    int argH; double g; argmax_gap6(s2, argH, g);
    bHf = 16.0f * idx_to_bits(argH);
    out[O_Hbl + (size_t)m * 64 + k] = bHf;
#pragma unroll
    for (int j = 0; j < 6; ++j)
      out[O_wH + (size_t)(m * 64 + k) * 6 + j] = (j == argH) ? 1.0f : 0.0f;
  } else {
    bHf = out[O_Hbl + (size_t)m * 64 + k];
  }
  if (f & 2) {
    double s2[6];
#pragma unroll
    for (int j = 0; j < 6; ++j) {
      const float u = bits_to_unif(jax_randbits(g3k0, g3k1, eH + j, 6291456u));
      s2[j] = ldd[j] - log(-log((double)u));
    }
    int argD; double g; argmax_gap6(s2, argD, g);
    bDf = 2.0f * idx_to_bits(argD);
    out[O_dbl + (size_t)m * 64 + k] = bDf;
#pragma unroll
    for (int j = 0; j < 6; ++j)
      out[O_wd + (size_t)(m * 64 + k) * 6 + j] = (j == argD) ? 1.0f : 0.0f;
  } else {
    bDf = out[O_dbl + (size_t)m * 64 + k];
  }

  float bYf;
  if (mf & 2) {  // Y flagged: f64 argY from the full wave's f64 logits
    double lys2[6];
#pragma unroll
    for (int j = 0; j < 6; ++j) lys2[j] = wave_sum_f64(lyd[j]);
    int argY = 0;
    if (k == 0) {
      double s2[6];
#pragma unroll
      for (int j = 0; j < 6; ++j) {
        const float u = bits_to_unif(jax_randbits(g1k0, g1k1, (uint32_t)(m * 6 + j), 98304u));
        s2[j] = lys2[j] * (1.0 / 64.0) - log(-log((double)u));
      }
      double g; argmax_gap6(s2, argY, g);
    }
    argY = __shfl(argY, 0);
    bYf = 16.0f * idx_to_bits(argY);
    if (k == 0) {
      out[O_yba + m] = bYf;
#pragma unroll
      for (int j = 0; j < 6; ++j) out[O_wy + m * 6 + j] = (j == argY) ? 1.0f : 0.0f;
    }
  } else {
    bYf = out[O_yba + m];
  }

  // eb row from final bits (same f32 op order as hot kernel)
  out[O_eb + (size_t)m * 64 + k] = (bYf * 0.015625f + bHf) + bDf;
}

// ---------------------------------------------------------------- LSQ quant
__device__ __forceinline__ int bits_to_idx(int bits) {
  return (bits <= 8) ? ((bits >> 1) - 1) : ((bits == 12) ? 4 : 5);
}

__device__ __forceinline__ float lsq1(float x, float ssv, float qn, float qp) {
  float t = x / ssv;
  t = fminf(fmaxf(t, qn), qp);
  return rintf(t) * ssv;
}

__global__ void k3_Hq(const float* __restrict__ Hm, const float* __restrict__ ss,
                      const float* __restrict__ Hbits, float* __restrict__ outHq) {
  const int id = blockIdx.x * blockDim.x + threadIdx.x;
  if (id >= 8388608) return;
  const int k = id & 63;
  const int m = id >> 9;
  const int bits = (int)Hbits[(size_t)m * 64 + k] >> 4;
  const int i = bits_to_idx(bits);
  const float ssv = ss[6 + i];
  const float qp = (float)((1 << (bits - 1)) - 1);
  const float qn = -(float)(1 << (bits - 1));
  const float2 x = ((const float2*)Hm)[id];
  float2 o;
  o.x = lsq1(x.x, ssv, qn, qp);
  o.y = lsq1(x.y, ssv, qn, qp);
  ((float2*)outHq)[id] = o;
}

__global__ void k4_vq(const float* __restrict__ v, const float* __restrict__ ss,
                      const float* __restrict__ dbits, float* __restrict__ outvq) {
  const int id = blockIdx.x * blockDim.x + threadIdx.x;
  if (id >= 1048576) return;
  const int bits = (int)dbits[id] >> 1;
  const int i = bits_to_idx(bits);
  const float ssv = ss[12 + i];
  const float qp = (float)((1 << (bits - 1)) - 1);
  const float qn = -(float)(1 << (bits - 1));
  const float2 x = ((const float2*)v)[id];
  float2 o;
  o.x = lsq1(x.x, ssv, qn, qp);
  o.y = lsq1(x.y, ssv, qn, qp);
  ((float2*)outvq)[id] = o;
}

__global__ void k5_yq(const float* __restrict__ y, const float* __restrict__ ss,
                      const float* __restrict__ ybits, float* __restrict__ outyq) {
  const int id = blockIdx.x * blockDim.x + threadIdx.x;
  if (id >= 131072) return;
  const int m = id >> 3;
  const int bits = (int)ybits[m] >> 4;
  const int i = bits_to_idx(bits);
  const float ssv = ss[i];
  const float qp = (float)((1 << (bits - 1)) - 1);
  const float qn = -(float)(1 << (bits - 1));
  const float2 x = ((const float2*)y)[id];
  float2 o;
  o.x = lsq1(x.x, ssv, qn, qp);
  o.y = lsq1(x.y, ssv, qn, qp);
  ((float2*)outyq)[id] = o;
}

// ---------------------------------------------------------------- launch
extern "C" void kernel_launch(void* const* d_in, const int* in_sizes, int n_in,
                              void* d_out, int out_size, void* d_ws, size_t ws_size,
                              hipStream_t stream) {
  const float* v   = (const float*)d_in[0];
  const float* Hm  = (const float*)d_in[1];
  const float* y   = (const float*)d_in[2];
  const float* snr = (const float*)d_in[3];
  const float* w1  = (const float*)d_in[4];
  const float* b1  = (const float*)d_in[5];
  const float* w2  = (const float*)d_in[6];
  const float* b2  = (const float*)d_in[7];
  const float* w3  = (const float*)d_in[8];
  const float* b3  = (const float*)d_in[9];
  const float* wy  = (const float*)d_in[10];
  const float* by  = (const float*)d_in[11];
  const float* wh  = (const float*)d_in[12];
  const float* bh  = (const float*)d_in[13];
  const float* wd  = (const float*)d_in[14];
  const float* bd  = (const float*)d_in[15];
  const float* sy  = (const float*)d_in[16];
  const float* sH  = (const float*)d_in[17];
  const float* sd  = (const float*)d_in[18];

  float* out = (float*)d_out;

  double* ws_partial = (double*)d_ws;
  double* ws_hpmean  = ws_partial + 32768;
  float*  ws_ss      = (float*)(ws_hpmean + 4096);
  uint32_t* ws_keys  = (uint32_t*)(ws_ss + 18);

  k0_setup<<<1, 64, 0, stream>>>(sy, sH, sd, ws_ss, ws_keys);
  k1a_hpower_partial<<<512, 128, 0, stream>>>(Hm, ws_partial);
  k1b_hpmean<<<16, 256, 0, stream>>>(ws_partial, ws_hpmean);
  k2_main<<<BL / 4, 256, 0, stream>>>(v, Hm, y, snr, w1, b1, w2, b2, w3, b3,
                                      wy, by, wh, bh, wd, bd, ws_hpmean, ws_keys, out);
  kfix<<<BL, 64, 0, stream>>>(v, Hm, y, snr, w1, b1, w2, b2, w3, b3,
                              wy, by, wh, bh, wd, bd, ws_hpmean, ws_keys, out);
  k3_Hq<<<32768, 256, 0, stream>>>(Hm, ws_ss, out + O_Hbl, out + O_Hq);
  k4_vq<<<4096, 256, 0, stream>>>(v, ws_ss, out + O_dbl, out + O_vq);
  k5_yq<<<512, 256, 0, stream>>>(y, ws_ss, out + O_yba, out + O_yq);
}

// Round 5
// 832.752 us; speedup vs baseline: 3.7141x; 2.1915x over previous
//
#include <hip/hip_runtime.h>
#include <cstdint>

// ============================================================================
// TripleAdaptiveQuantizerV5 — round 5: fast f64 fallback (kfix rebuilt).
//
// R4 post-mortem: kfix = 1250us = ONE flagged block's serial latency chain
// (#pragma unroll 1 + per-FMA global weight load + scratch-spilled f64
// activation arrays; VGPR=40, VALUBusy 1.5%). R5 kfix: same LDS-gemm
// structure as k2 but f64 — weights staged in LDS (f32, exact convert),
// activations f64 [i][k] in LDS, 4x4 f64 register tiles. Each output keeps
// a single i-ascending FMA chain (deterministic f64). Grid 2048 x 8 m/block,
// block-uniform flag precheck. k2/k0/k1/k3-5 unchanged from passing R4.
// ============================================================================

#define JAX_PARTITIONABLE 1

constexpr int BL = 64 * 256;  // 16384 (B*L)

// Output offsets (floats)
constexpr long long O_vq  = 0;
constexpr long long O_Hq  = 2097152;
constexpr long long O_yq  = 18874368;
constexpr long long O_eb  = 19136512;
constexpr long long O_wy  = 20185088;
constexpr long long O_wH  = 20283392;
constexpr long long O_wd  = 26574848;
constexpr long long O_yba = 32866304;
constexpr long long O_Hbl = 32882688;
constexpr long long O_dbl = 33931264;

// flag stash inside the v_q region (k4 overwrites all of v_q afterwards)
constexpr long long F_SAMPLE = 0;        // 1048576 bytes, 1 per (m,k)
constexpr long long F_M      = 1048576;  // 16384 bytes, 1 per m

#define MARGIN_THETA 3e-4

// ---------------------------------------------------------------- threefry
__device__ __forceinline__ uint32_t rotl32(uint32_t v, int d) {
  return (v << d) | (v >> (32 - d));
}

__device__ __forceinline__ void threefry2x32(uint32_t k0, uint32_t k1,
                                             uint32_t x0, uint32_t x1,
                                             uint32_t& o0, uint32_t& o1) {
  const uint32_t ks2 = k0 ^ k1 ^ 0x1BD11BDAu;
  x0 += k0; x1 += k1;
  x0 += x1; x1 = rotl32(x1, 13); x1 ^= x0;
  x0 += x1; x1 = rotl32(x1, 15); x1 ^= x0;
  x0 += x1; x1 = rotl32(x1, 26); x1 ^= x0;
  x0 += x1; x1 = rotl32(x1, 6);  x1 ^= x0;
  x0 += k1; x1 += ks2 + 1u;
  x0 += x1; x1 = rotl32(x1, 17); x1 ^= x0;
  x0 += x1; x1 = rotl32(x1, 29); x1 ^= x0;
  x0 += x1; x1 = rotl32(x1, 16); x1 ^= x0;
  x0 += x1; x1 = rotl32(x1, 24); x1 ^= x0;
  x0 += ks2; x1 += k0 + 2u;
  x0 += x1; x1 = rotl32(x1, 13); x1 ^= x0;
  x0 += x1; x1 = rotl32(x1, 15); x1 ^= x0;
  x0 += x1; x1 = rotl32(x1, 26); x1 ^= x0;
  x0 += x1; x1 = rotl32(x1, 6);  x1 ^= x0;
  x0 += k0; x1 += k1 + 3u;
  x0 += x1; x1 = rotl32(x1, 17); x1 ^= x0;
  x0 += x1; x1 = rotl32(x1, 29); x1 ^= x0;
  x0 += x1; x1 = rotl32(x1, 16); x1 ^= x0;
  x0 += x1; x1 = rotl32(x1, 24); x1 ^= x0;
  x0 += k1; x1 += ks2 + 4u;
  x0 += x1; x1 = rotl32(x1, 13); x1 ^= x0;
  x0 += x1; x1 = rotl32(x1, 15); x1 ^= x0;
  x0 += x1; x1 = rotl32(x1, 26); x1 ^= x0;
  x0 += x1; x1 = rotl32(x1, 6);  x1 ^= x0;
  x0 += ks2; x1 += k0 + 5u;
  o0 = x0; o1 = x1;
}

__device__ __forceinline__ uint32_t jax_randbits(uint32_t k0, uint32_t k1,
                                                 uint32_t e, uint32_t size) {
#if JAX_PARTITIONABLE
  (void)size;
  uint32_t o0, o1;
  threefry2x32(k0, k1, 0u, e, o0, o1);
  return o0 ^ o1;
#else
  const uint32_t half = size >> 1;
  uint32_t o0, o1;
  if (e < half) { threefry2x32(k0, k1, e, e + half, o0, o1); return o0; }
  threefry2x32(k0, k1, e - half, e, o0, o1); return o1;
#endif
}

// exact f32 replication of jax.random.uniform(minval=1e-10, maxval=1.0)
__device__ __forceinline__ float bits_to_unif(uint32_t bits) {
  float f = __uint_as_float((bits >> 9) | 0x3f800000u) - 1.0f;
  return fmaxf(1e-10f, f + 1e-10f);
}

// ---------------------------------------------------------------- helpers
__device__ __forceinline__ double wave_sum_f64(double x) {
#pragma unroll
  for (int off = 32; off > 0; off >>= 1) x += __shfl_xor(x, off);
  return x;
}

__device__ __forceinline__ void argmax_gap6(const double* s, int& arg, double& gap) {
  int a = 0;
#pragma unroll
  for (int j = 1; j < 6; ++j) if (s[j] > s[a]) a = j;
  double second = -1e300;
#pragma unroll
  for (int j = 0; j < 6; ++j) if (j != a && s[j] > second) second = s[j];
  arg = a; gap = s[a] - second;
}

__device__ __forceinline__ float idx_to_bits(int i) {
  return (float)((i < 4) ? 2 * (i + 1) : (i == 4 ? 12 : 16));
}

// ---------------------------------------------------------------- K0: ss + keys
__global__ void k0_setup(const float* __restrict__ sy, const float* __restrict__ sH,
                         const float* __restrict__ sd, float* __restrict__ ss,
                         uint32_t* __restrict__ keys) {
  const int t = threadIdx.x;
  if (t < 18) {
    const int tensor = t / 6, i = t % 6;
    const int qp_[6] = {1, 7, 31, 127, 2047, 32767};
    const long long sizes[3] = {262144LL, 16777216LL, 2097152LL};  // y, H, v
    const float* sarr = tensor == 0 ? sy : (tensor == 1 ? sH : sd);
    const double g64 = 1.0 / sqrt((double)(sizes[tensor] * (long long)qp_[i]));
    const float g32 = (float)g64;
    const float s = sarr[i];
    const float t1 = s * g32;
    ss[t] = t1 + (s - t1);  // _grad_scale forward, exact f32 sequence
  }
#if JAX_PARTITIONABLE
  if (t >= 32 && t < 35) {
    uint32_t o0, o1;
    threefry2x32(0u, 42u, 0u, (uint32_t)(t - 32), o0, o1);
    keys[(t - 32) * 2 + 0] = o0;
    keys[(t - 32) * 2 + 1] = o1;
  }
#else
  if (t == 32) {
    uint32_t a0, b0, a1, b1, a2, b2;
    threefry2x32(0u, 42u, 0u, 3u, a0, b0);
    threefry2x32(0u, 42u, 1u, 4u, a1, b1);
    threefry2x32(0u, 42u, 2u, 5u, a2, b2);
    keys[0] = a0; keys[1] = a1;
    keys[2] = a2; keys[3] = b0;
    keys[4] = b1; keys[5] = b2;
  }
#endif
}

// ---------------------------------------------------------------- K1: hp_mean
__global__ __launch_bounds__(128) void k1a_hpower_partial(
    const float* __restrict__ Hm, double* __restrict__ partial) {
  const int blk = blockIdx.x;       // 512 = 64 b * 8 l-chunks
  const int b = blk >> 3, lc = blk & 7;
  const int t = threadIdx.x;        // 128 = (k,c)
  const float* base = Hm + (size_t)(b * 256 + lc * 32) * 1024;
  double acc = 0.0;
  for (int l = 0; l < 32; ++l) {
#pragma unroll
    for (int n = 0; n < 8; ++n) {
      const float x = base[(size_t)l * 1024 + n * 128 + t];
      acc = fma((double)x, (double)x, acc);
    }
  }
  const double other = __shfl_xor(acc, 1);
  if ((t & 1) == 0) partial[(size_t)blk * 64 + (t >> 1)] = acc + other;
}

__global__ void k1b_hpmean(const double* __restrict__ partial,
                           double* __restrict__ hp_mean) {
  const int id = blockIdx.x * blockDim.x + threadIdx.x;  // 4096 = b*64+k
  if (id >= 4096) return;
  const int b = id >> 6, k = id & 63;
  double s = 0.0;
#pragma unroll
  for (int lc = 0; lc < 8; ++lc) s += partial[(size_t)(b * 8 + lc) * 64 + k];
  hp_mean[id] = s * (1.0 / 256.0);
}

// ---------------------------------------------------------------- GEMM tile
// out[k][j] = act(bias[j] + sum_i in[k][i]*W[j][i]); 256 thr = 16x16 tiles of
// 4x4. inT: LDS [i][k] stride 68; WT: LDS [i][j] stride 64 (transposed).
template <int NI, bool RELU>
__device__ __forceinline__ void gemm64(const float* __restrict__ inT,
                                       const float* __restrict__ WT,
                                       const float* __restrict__ bias,
                                       float* __restrict__ outT, int t) {
  const int k0 = (t & 15) * 4;
  const int j0 = (t >> 4) * 4;
  float acc[16];
#pragma unroll
  for (int jj = 0; jj < 4; ++jj) {
    const float bj = bias[j0 + jj];
#pragma unroll
    for (int kk = 0; kk < 4; ++kk) acc[jj * 4 + kk] = bj;
  }
#pragma unroll 16
  for (int i = 0; i < NI; ++i) {
    const float4 x  = *(const float4*)&inT[i * 68 + k0];
    const float4 wv = *(const float4*)&WT[i * 64 + j0];
    acc[0]  = fmaf(wv.x, x.x, acc[0]);
    acc[1]  = fmaf(wv.x, x.y, acc[1]);
    acc[2]  = fmaf(wv.x, x.z, acc[2]);
    acc[3]  = fmaf(wv.x, x.w, acc[3]);
    acc[4]  = fmaf(wv.y, x.x, acc[4]);
    acc[5]  = fmaf(wv.y, x.y, acc[5]);
    acc[6]  = fmaf(wv.y, x.z, acc[6]);
    acc[7]  = fmaf(wv.y, x.w, acc[7]);
    acc[8]  = fmaf(wv.z, x.x, acc[8]);
    acc[9]  = fmaf(wv.z, x.y, acc[9]);
    acc[10] = fmaf(wv.z, x.z, acc[10]);
    acc[11] = fmaf(wv.z, x.w, acc[11]);
    acc[12] = fmaf(wv.w, x.x, acc[12]);
    acc[13] = fmaf(wv.w, x.y, acc[13]);
    acc[14] = fmaf(wv.w, x.z, acc[14]);
    acc[15] = fmaf(wv.w, x.w, acc[15]);
  }
#pragma unroll
  for (int jj = 0; jj < 4; ++jj) {
    float4 r;
    r.x = acc[jj * 4 + 0];
    r.y = acc[jj * 4 + 1];
    r.z = acc[jj * 4 + 2];
    r.w = acc[jj * 4 + 3];
    if (RELU) {
      r.x = fmaxf(r.x, 0.0f); r.y = fmaxf(r.y, 0.0f);
      r.z = fmaxf(r.z, 0.0f); r.w = fmaxf(r.w, 0.0f);
    }
    *(float4*)&outT[(j0 + jj) * 68 + k0] = r;
  }
}

// f64 variant for kfix: weights f32 in LDS (exact convert), act f64 [i][k].
// Each (j,k) accumulator is one i-ascending f64 FMA chain (matches the
// reference rolled-loop chain per output).
template <int NI>
__device__ __forceinline__ void gemm64_f64(const double* __restrict__ inT,
                                           const float* __restrict__ WT,
                                           const float* __restrict__ bias,
                                           double* __restrict__ outT, int t) {
  const int k0 = (t & 15) * 4;
  const int j0 = (t >> 4) * 4;
  double acc[16];
#pragma unroll
  for (int jj = 0; jj < 4; ++jj) {
    const double bj = (double)bias[j0 + jj];
#pragma unroll
    for (int kk = 0; kk < 4; ++kk) acc[jj * 4 + kk] = bj;
  }
#pragma unroll 8
  for (int i = 0; i < NI; ++i) {
    const double x0 = inT[i * 68 + k0 + 0];
    const double x1 = inT[i * 68 + k0 + 1];
    const double x2 = inT[i * 68 + k0 + 2];
    const double x3 = inT[i * 68 + k0 + 3];
    const float4 wf = *(const float4*)&WT[i * 64 + j0];
    const double w0 = (double)wf.x, w1 = (double)wf.y;
    const double w2 = (double)wf.z, w3 = (double)wf.w;
    acc[0]  = fma(w0, x0, acc[0]);
    acc[1]  = fma(w0, x1, acc[1]);
    acc[2]  = fma(w0, x2, acc[2]);
    acc[3]  = fma(w0, x3, acc[3]);
    acc[4]  = fma(w1, x0, acc[4]);
    acc[5]  = fma(w1, x1, acc[5]);
    acc[6]  = fma(w1, x2, acc[6]);
    acc[7]  = fma(w1, x3, acc[7]);
    acc[8]  = fma(w2, x0, acc[8]);
    acc[9]  = fma(w2, x1, acc[9]);
    acc[10] = fma(w2, x2, acc[10]);
    acc[11] = fma(w2, x3, acc[11]);
    acc[12] = fma(w3, x0, acc[12]);
    acc[13] = fma(w3, x1, acc[13]);
    acc[14] = fma(w3, x2, acc[14]);
    acc[15] = fma(w3, x3, acc[15]);
  }
#pragma unroll
  for (int jj = 0; jj < 4; ++jj) {
#pragma unroll
    for (int kk = 0; kk < 4; ++kk) {
      const double a = acc[jj * 4 + kk];
      outT[(j0 + jj) * 68 + k0 + kk] = a > 0.0 ? a : 0.0;  // same relu as ref
    }
  }
}

// heads: 18 rows (padded to 20), split across the 4 waves; lane = k.
__device__ __forceinline__ void heads20(const float* __restrict__ actT,
                                        const float* __restrict__ whT,
                                        const float* __restrict__ by,
                                        const float* __restrict__ bh,
                                        const float* __restrict__ bd,
                                        float* __restrict__ headP, int t) {
  const int k = t & 63, w = t >> 6;
  float acc[5];
#pragma unroll
  for (int q = 0; q < 5; ++q) {
    const int r = w + 4 * q;
    acc[q] = (r < 6) ? by[r] : (r < 12) ? bh[r - 6] : (r < 18) ? bd[r - 12] : 0.0f;
  }
#pragma unroll 8
  for (int i = 0; i < 64; ++i) {
    const float x = actT[i * 68 + k];
#pragma unroll
    for (int q = 0; q < 5; ++q)
      acc[q] = fmaf(x, whT[(w + 4 * q) * 64 + i], acc[q]);
  }
#pragma unroll
  for (int q = 0; q < 5; ++q) {
    const int r = w + 4 * q;
    if (r < 18) headP[k * 20 + r] = acc[q];
  }
}

__device__ __forceinline__ void heads20_f64(const double* __restrict__ actT,
                                            const float* __restrict__ whT,
                                            const float* __restrict__ by,
                                            const float* __restrict__ bh,
                                            const float* __restrict__ bd,
                                            double* __restrict__ headP, int t) {
  const int k = t & 63, w = t >> 6;
  double acc[5];
#pragma unroll
  for (int q = 0; q < 5; ++q) {
    const int r = w + 4 * q;
    acc[q] = (r < 6) ? (double)by[r]
           : (r < 12) ? (double)bh[r - 6]
           : (r < 18) ? (double)bd[r - 12] : 0.0;
  }
#pragma unroll 8
  for (int i = 0; i < 64; ++i) {
    const double x = actT[i * 68 + k];
#pragma unroll
    for (int q = 0; q < 5; ++q)
      acc[q] = fma(x, (double)whT[(w + 4 * q) * 64 + i], acc[q]);
  }
#pragma unroll
  for (int q = 0; q < 5; ++q) {
    const int r = w + 4 * q;
    if (r < 18) headP[k * 20 + r] = acc[q];
  }
}

// ---------------------------------------------------------------- K2: main
// 4 m per 256-thread block; grid = 4096. Each wave owns one m's selection.
__global__ __launch_bounds__(256, 2) void k2_main(
    const float* __restrict__ v, const float* __restrict__ Hm,
    const float* __restrict__ y, const float* __restrict__ snr,
    const float* __restrict__ w1, const float* __restrict__ b1,
    const float* __restrict__ w2, const float* __restrict__ b2,
    const float* __restrict__ w3, const float* __restrict__ b3,
    const float* __restrict__ wy, const float* __restrict__ by,
    const float* __restrict__ wh, const float* __restrict__ bh,
    const float* __restrict__ wd, const float* __restrict__ bd,
    const double* __restrict__ hp_mean, const uint32_t* __restrict__ keys,
    float* __restrict__ out) {
  const int t = threadIdx.x;
  const int lane = t & 63;
  const int wvx = t >> 6;
  const int m0 = blockIdx.x * 4;

  __shared__ __align__(16) float smem[20032];
  float* w1T   = smem;           // 576   [i<9][j]
  float* w2T   = smem + 576;     // 4096  [i][j]
  float* w3T   = smem + 4672;    // 4096  [i][j]
  float* whT   = smem + 8768;    // 1280  [r<20][i]
  float* actA  = smem + 10048;   // 4352  [row][k], stride 68
  float* actB  = smem + 14400;   // 4352
  float* headP = smem + 18752;   // 1280  [k][20]
  double* hp4  = (double*)actB;  // per-mc alias (consumed before L1 writes)

  for (int idx = t; idx < 576; idx += 256) {
    const int i = idx >> 6, j = idx & 63;
    w1T[idx] = w1[j * 9 + i];
  }
  for (int idx = t; idx < 4096; idx += 256) {
    const int i = idx >> 6, j = idx & 63;
    w2T[idx] = w2[j * 64 + i];
    w3T[idx] = w3[j * 64 + i];
  }
  for (int idx = t; idx < 1280; idx += 256) {
    const int r = idx >> 6, i = idx & 63;
    whT[idx] = (r < 6) ? wy[r * 64 + i]
             : (r < 12) ? wh[(r - 6) * 64 + i]
             : (r < 18) ? wd[(r - 12) * 64 + i] : 0.0f;
  }

  float ly[6], lh[6], ld[6];
#pragma unroll 1
  for (int mc = 0; mc < 4; ++mc) {
    const int m = m0 + mc;
    {
      const float2* Hp = (const float2*)Hm + (size_t)m * 512;
      double acc = 0.0;
#pragma unroll
      for (int nn = 0; nn < 2; ++nn) {
        const float2 h2v = Hp[(2 * wvx + nn) * 64 + lane];
        acc = fma((double)h2v.x, (double)h2v.x, acc);
        acc = fma((double)h2v.y, (double)h2v.y, acc);
      }
      __syncthreads();
      hp4[wvx * 64 + lane] = acc;
    }
    __syncthreads();

    if (wvx == mc) {
      const double hp = ((hp4[lane] + hp4[64 + lane]) + hp4[128 + lane]) + hp4[192 + lane];
      const double tp = wave_sum_f64(hp);
      double ypart = 0.0;
      if (lane < 16) { const double yv = (double)y[m * 16 + lane]; ypart = yv * yv; }
      const double yp = wave_sum_f64(ypart);
      const float2 vv = ((const float2*)v)[m * 64 + lane];
      const float snrv = snr[m * 64 + lane];
      const double hpm = hp_mean[(m >> 8) * 64 + lane];
      float f[9];
      f[0] = (float)vv.x;
      f[1] = (float)vv.y;
      f[2] = snrv;
      f[3] = (float)hp;
      f[4] = (float)hpm;
      f[5] = (float)log1p(hp / ((tp - hp) + 1e-10));
      f[6] = (float)log1p(tp);
      f[7] = (float)log1p(yp);
      f[8] = (float)sqrt(fma((double)vv.x, (double)vv.x,
                             fma((double)vv.y, (double)vv.y, 1e-10)));
#pragma unroll
      for (int i = 0; i < 9; ++i) actA[i * 68 + lane] = f[i];
    }
    __syncthreads();

    gemm64<9, true>(actA, w1T, b1, actB, t);
    __syncthreads();
    gemm64<64, true>(actB, w2T, b2, actA, t);
    __syncthreads();
    gemm64<64, true>(actA, w3T, b3, actB, t);
    __syncthreads();
    heads20(actB, whT, by, bh, bd, headP, t);
    __syncthreads();

    if (wvx == mc) {
#pragma unroll
      for (int j = 0; j < 6; ++j) {
        ly[j] = headP[lane * 20 + j];
        lh[j] = headP[lane * 20 + 6 + j];
        ld[j] = headP[lane * 20 + 12 + j];
      }
    }
  }

  // ---- phase C: each wave handles its own m ----
  const int m = m0 + wvx;
  const int k = lane;

  const uint32_t g1k0 = keys[0], g1k1 = keys[1];
  const uint32_t g2k0 = keys[2], g2k1 = keys[3];
  const uint32_t g3k0 = keys[4], g3k1 = keys[5];

  double sH[6], sD[6];
  const uint32_t eH = (uint32_t)(m * 64 + k) * 6u;
#pragma unroll
  for (int j = 0; j < 6; ++j) {
    const float u = bits_to_unif(jax_randbits(g2k0, g2k1, eH + j, 6291456u));
    sH[j] = (double)lh[j] + (double)(-logf(-logf(u)));
  }
#pragma unroll
  for (int j = 0; j < 6; ++j) {
    const float u = bits_to_unif(jax_randbits(g3k0, g3k1, eH + j, 6291456u));
    sD[j] = (double)ld[j] + (double)(-logf(-logf(u)));
  }
  int argH, argD; double gapH, gapD;
  argmax_gap6(sH, argH, gapH);
  argmax_gap6(sD, argD, gapD);

  double lysum[6];
#pragma unroll
  for (int j = 0; j < 6; ++j) lysum[j] = wave_sum_f64((double)ly[j]);

  int argY = 0; double gapY = 1e30;
  if (k == 0) {
    double sY[6];
#pragma unroll
    for (int j = 0; j < 6; ++j) {
      const float u = bits_to_unif(jax_randbits(g1k0, g1k1, (uint32_t)(m * 6 + j), 98304u));
      sY[j] = lysum[j] * (1.0 / 64.0) - log(-log((double)u));
    }
    argmax_gap6(sY, argY, gapY);
  }
  const int needY = __shfl((k == 0 && gapY < MARGIN_THETA) ? 1 : 0, 0);
  const bool fH = gapH < MARGIN_THETA;
  const bool fD = gapD < MARGIN_THETA;

  uint8_t* flags = (uint8_t*)(out + O_vq);
  flags[F_SAMPLE + (size_t)m * 64 + k] = (uint8_t)((fH ? 1 : 0) | (fD ? 2 : 0));
  const bool anyHD = __ballot(fH || fD) != 0ull;
  if (k == 0)
    flags[F_M + m] = (uint8_t)(((anyHD || needY) ? 1 : 0) | (needY ? 2 : 0));

  argY = __shfl(argY, 0);

  const float bY = 16.0f * idx_to_bits(argY);   // 2*N*bits
  const float bH = 16.0f * idx_to_bits(argH);
  const float bD = 2.0f * idx_to_bits(argD);

  if (k == 0) {
    out[O_yba + m] = bY;
#pragma unroll
    for (int j = 0; j < 6; ++j) out[O_wy + m * 6 + j] = (j == argY) ? 1.0f : 0.0f;
  }
  out[O_Hbl + (size_t)m * 64 + k] = bH;
  out[O_dbl + (size_t)m * 64 + k] = bD;
  out[O_eb + (size_t)m * 64 + k] = (bY * 0.015625f + bH) + bD;
#pragma unroll
  for (int j = 0; j < 6; ++j) {
    out[O_wH + (size_t)(m * 64 + k) * 6 + j] = (j == argH) ? 1.0f : 0.0f;
    out[O_wd + (size_t)(m * 64 + k) * 6 + j] = (j == argD) ? 1.0f : 0.0f;
  }
}

// ---------------------------------------------------------------- kfix
// 256-thread block handles 8 m's; per flagged m runs the f64 LDS-gemm MLP.
__global__ __launch_bounds__(256, 1) void kfix(
    const float* __restrict__ v, const float* __restrict__ Hm,
    const float* __restrict__ y, const float* __restrict__ snr,
    const float* __restrict__ w1, const float* __restrict__ b1,
    const float* __restrict__ w2, const float* __restrict__ b2,
    const float* __restrict__ w3, const float* __restrict__ b3,
    const float* __restrict__ wy, const float* __restrict__ by,
    const float* __restrict__ wh, const float* __restrict__ bh,
    const float* __restrict__ wd, const float* __restrict__ bd,
    const double* __restrict__ hp_mean, const uint32_t* __restrict__ keys,
    float* __restrict__ out) {
  const int t = threadIdx.x;
  const int lane = t & 63;
  const int wvx = t >> 6;
  const int m0 = blockIdx.x * 8;
  const uint8_t* flags = (const uint8_t*)(out + O_vq);

  __shared__ uint32_t mfs[8];
  __shared__ __align__(32) char smem[120064];
  float*  w1T     = (float*)smem;                 // 576 f  [i<9][j]
  float*  w2T     = (float*)(smem + 2304);        // 4096 f [i][j]
  float*  w3T     = (float*)(smem + 18688);       // 4096 f [i][j]
  float*  whT     = (float*)(smem + 35072);       // 1280 f [r<20][i]
  double* actA64  = (double*)(smem + 40192);      // 64x68 d [row][k]
  double* actB64  = (double*)(smem + 75008);      // 64x68 d
  double* headP64 = (double*)(smem + 109824);     // 64x20 d [k][20]
  double* hp4     = actB64;                       // alias (pre-L1 only)

  if (t < 8) mfs[t] = flags[F_M + m0 + t];
  __syncthreads();
  bool any = false;
#pragma unroll
  for (int i = 0; i < 8; ++i) any |= (mfs[i] != 0);
  if (!any) return;

  // stage weights once (same transposed layouts as k2)
  for (int idx = t; idx < 576; idx += 256) {
    const int i = idx >> 6, j = idx & 63;
    w1T[idx] = w1[j * 9 + i];
  }
  for (int idx = t; idx < 4096; idx += 256) {
    const int i = idx >> 6, j = idx & 63;
    w2T[idx] = w2[j * 64 + i];
    w3T[idx] = w3[j * 64 + i];
  }
  for (int idx = t; idx < 1280; idx += 256) {
    const int r = idx >> 6, i = idx & 63;
    whT[idx] = (r < 6) ? wy[r * 64 + i]
             : (r < 12) ? wh[(r - 6) * 64 + i]
             : (r < 18) ? wd[(r - 12) * 64 + i] : 0.0f;
  }

#pragma unroll 1
  for (int mi = 0; mi < 8; ++mi) {
    const uint32_t mf = mfs[mi];
    if (mf == 0) continue;  // block-uniform
    const int m = m0 + mi;

    // hp partials, identical op order to k2
    {
      const float2* Hp = (const float2*)Hm + (size_t)m * 512;
      double acc = 0.0;
#pragma unroll
      for (int nn = 0; nn < 2; ++nn) {
        const float2 h2v = Hp[(2 * wvx + nn) * 64 + lane];
        acc = fma((double)h2v.x, (double)h2v.x, acc);
        acc = fma((double)h2v.y, (double)h2v.y, acc);
      }
      __syncthreads();  // weights staged / prior-m reads done before actB reuse
      hp4[wvx * 64 + lane] = acc;
    }
    __syncthreads();

    // wave 0: f64 features -> actA64 rows 0..8
    if (t < 64) {
      const double hp = ((hp4[lane] + hp4[64 + lane]) + hp4[128 + lane]) + hp4[192 + lane];
      const double tp = wave_sum_f64(hp);
      double ypart = 0.0;
      if (lane < 16) { const double yv = (double)y[m * 16 + lane]; ypart = yv * yv; }
      const double yp = wave_sum_f64(ypart);
      const float2 vv = ((const float2*)v)[m * 64 + lane];
      const float snrv = snr[m * 64 + lane];
      const double hpm = hp_mean[(m >> 8) * 64 + lane];
      double f[9];
      f[0] = (double)vv.x;
      f[1] = (double)vv.y;
      f[2] = (double)snrv;
      f[3] = hp;
      f[4] = hpm;
      f[5] = log1p(hp / ((tp - hp) + 1e-10));
      f[6] = log1p(tp);
      f[7] = log1p(yp);
      f[8] = sqrt(fma((double)vv.x, (double)vv.x,
                      fma((double)vv.y, (double)vv.y, 1e-10)));
#pragma unroll
      for (int i = 0; i < 9; ++i) actA64[i * 68 + lane] = f[i];
    }
    __syncthreads();

    gemm64_f64<9>(actA64, w1T, b1, actB64, t);
    __syncthreads();
    gemm64_f64<64>(actB64, w2T, b2, actA64, t);
    __syncthreads();
    gemm64_f64<64>(actA64, w3T, b3, actB64, t);
    __syncthreads();
    heads20_f64(actB64, whT, by, bh, bd, headP64, t);
    __syncthreads();

    // wave 0: refine flagged selections
    if (t < 64) {
      const int k = lane;
      const uint8_t f = flags[F_SAMPLE + (size_t)m * 64 + k];
      double lyd[6], lhd[6], ldd[6];
#pragma unroll
      for (int j = 0; j < 6; ++j) {
        lyd[j] = headP64[k * 20 + j];
        lhd[j] = headP64[k * 20 + 6 + j];
        ldd[j] = headP64[k * 20 + 12 + j];
      }
      const uint32_t g1k0 = keys[0], g1k1 = keys[1];
      const uint32_t g2k0 = keys[2], g2k1 = keys[3];
      const uint32_t g3k0 = keys[4], g3k1 = keys[5];
      const uint32_t eH = (uint32_t)(m * 64 + k) * 6u;

      float bHf, bDf;
      if (f & 1) {
        double s2[6];
#pragma unroll
        for (int j = 0; j < 6; ++j) {
          const float u = bits_to_unif(jax_randbits(g2k0, g2k1, eH + j, 6291456u));
          s2[j] = lhd[j] - log(-log((double)u));
        }
        int argH; double g; argmax_gap6(s2, argH, g);
        bHf = 16.0f * idx_to_bits(argH);
        out[O_Hbl + (size_t)m * 64 + k] = bHf;
#pragma unroll
        for (int j = 0; j < 6; ++j)
          out[O_wH + (size_t)(m * 64 + k) * 6 + j] = (j == argH) ? 1.0f : 0.0f;
      } else {
        bHf = out[O_Hbl + (size_t)m * 64 + k];
      }
      if (f & 2) {
        double s2[6];
#pragma unroll
        for (int j = 0; j < 6; ++j) {
          const float u = bits_to_unif(jax_randbits(g3k0, g3k1, eH + j, 6291456u));
          s2[j] = ldd[j] - log(-log((double)u));
        }
        int argD; double g; argmax_gap6(s2, argD, g);
        bDf = 2.0f * idx_to_bits(argD);
        out[O_dbl + (size_t)m * 64 + k] = bDf;
#pragma unroll
        for (int j = 0; j < 6; ++j)
          out[O_wd + (size_t)(m * 64 + k) * 6 + j] = (j == argD) ? 1.0f : 0.0f;
      } else {
        bDf = out[O_dbl + (size_t)m * 64 + k];
      }

      float bYf;
      if (mf & 2) {
        double lys2[6];
#pragma unroll
        for (int j = 0; j < 6; ++j) lys2[j] = wave_sum_f64(lyd[j]);
        int argY = 0;
        if (k == 0) {
          double s2[6];
#pragma unroll
          for (int j = 0; j < 6; ++j) {
            const float u = bits_to_unif(jax_randbits(g1k0, g1k1, (uint32_t)(m * 6 + j), 98304u));
            s2[j] = lys2[j] * (1.0 / 64.0) - log(-log((double)u));
          }
          double g; argmax_gap6(s2, argY, g);
        }
        argY = __shfl(argY, 0);
        bYf = 16.0f * idx_to_bits(argY);
        if (k == 0) {
          out[O_yba + m] = bYf;
#pragma unroll
          for (int j = 0; j < 6; ++j) out[O_wy + m * 6 + j] = (j == argY) ? 1.0f : 0.0f;
        }
      } else {
        bYf = out[O_yba + m];
      }

      out[O_eb + (size_t)m * 64 + k] = (bYf * 0.015625f + bHf) + bDf;
    }
    __syncthreads();  // headP64/actB64 safe before next mi reuses them
  }
}

// ---------------------------------------------------------------- LSQ quant
__device__ __forceinline__ int bits_to_idx(int bits) {
  return (bits <= 8) ? ((bits >> 1) - 1) : ((bits == 12) ? 4 : 5);
}

__device__ __forceinline__ float lsq1(float x, float ssv, float qn, float qp) {
  float t = x / ssv;
  t = fminf(fmaxf(t, qn), qp);
  return rintf(t) * ssv;
}

__global__ void k3_Hq(const float* __restrict__ Hm, const float* __restrict__ ss,
                      const float* __restrict__ Hbits, float* __restrict__ outHq) {
  const int id = blockIdx.x * blockDim.x + threadIdx.x;
  if (id >= 8388608) return;
  const int k = id & 63;
  const int m = id >> 9;
  const int bits = (int)Hbits[(size_t)m * 64 + k] >> 4;
  const int i = bits_to_idx(bits);
  const float ssv = ss[6 + i];
  const float qp = (float)((1 << (bits - 1)) - 1);
  const float qn = -(float)(1 << (bits - 1));
  const float2 x = ((const float2*)Hm)[id];
  float2 o;
  o.x = lsq1(x.x, ssv, qn, qp);
  o.y = lsq1(x.y, ssv, qn, qp);
  ((float2*)outHq)[id] = o;
}

__global__ void k4_vq(const float* __restrict__ v, const float* __restrict__ ss,
                      const float* __restrict__ dbits, float* __restrict__ outvq) {
  const int id = blockIdx.x * blockDim.x + threadIdx.x;
  if (id >= 1048576) return;
  const int bits = (int)dbits[id] >> 1;
  const int i = bits_to_idx(bits);
  const float ssv = ss[12 + i];
  const float qp = (float)((1 << (bits - 1)) - 1);
  const float qn = -(float)(1 << (bits - 1));
  const float2 x = ((const float2*)v)[id];
  float2 o;
  o.x = lsq1(x.x, ssv, qn, qp);
  o.y = lsq1(x.y, ssv, qn, qp);
  ((float2*)outvq)[id] = o;
}

__global__ void k5_yq(const float* __restrict__ y, const float* __restrict__ ss,
                      const float* __restrict__ ybits, float* __restrict__ outyq) {
  const int id = blockIdx.x * blockDim.x + threadIdx.x;
  if (id >= 131072) return;
  const int m = id >> 3;
  const int bits = (int)ybits[m] >> 4;
  const int i = bits_to_idx(bits);
  const float ssv = ss[i];
  const float qp = (float)((1 << (bits - 1)) - 1);
  const float qn = -(float)(1 << (bits - 1));
  const float2 x = ((const float2*)y)[id];
  float2 o;
  o.x = lsq1(x.x, ssv, qn, qp);
  o.y = lsq1(x.y, ssv, qn, qp);
  ((float2*)outyq)[id] = o;
}

// ---------------------------------------------------------------- launch
extern "C" void kernel_launch(void* const* d_in, const int* in_sizes, int n_in,
                              void* d_out, int out_size, void* d_ws, size_t ws_size,
                              hipStream_t stream) {
  const float* v   = (const float*)d_in[0];
  const float* Hm  = (const float*)d_in[1];
  const float* y   = (const float*)d_in[2];
  const float* snr = (const float*)d_in[3];
  const float* w1  = (const float*)d_in[4];
  const float* b1  = (const float*)d_in[5];
  const float* w2  = (const float*)d_in[6];
  const float* b2  = (const float*)d_in[7];
  const float* w3  = (const float*)d_in[8];
  const float* b3  = (const float*)d_in[9];
  const float* wy  = (const float*)d_in[10];
  const float* by  = (const float*)d_in[11];
  const float* wh  = (const float*)d_in[12];
  const float* bh  = (const float*)d_in[13];
  const float* wd  = (const float*)d_in[14];
  const float* bd  = (const float*)d_in[15];
  const float* sy  = (const float*)d_in[16];
  const float* sH  = (const float*)d_in[17];
  const float* sd  = (const float*)d_in[18];

  float* out = (float*)d_out;

  double* ws_partial = (double*)d_ws;
  double* ws_hpmean  = ws_partial + 32768;
  float*  ws_ss      = (float*)(ws_hpmean + 4096);
  uint32_t* ws_keys  = (uint32_t*)(ws_ss + 18);

  k0_setup<<<1, 64, 0, stream>>>(sy, sH, sd, ws_ss, ws_keys);
  k1a_hpower_partial<<<512, 128, 0, stream>>>(Hm, ws_partial);
  k1b_hpmean<<<16, 256, 0, stream>>>(ws_partial, ws_hpmean);
  k2_main<<<BL / 4, 256, 0, stream>>>(v, Hm, y, snr, w1, b1, w2, b2, w3, b3,
                                      wy, by, wh, bh, wd, bd, ws_hpmean, ws_keys, out);
  kfix<<<BL / 8, 256, 0, stream>>>(v, Hm, y, snr, w1, b1, w2, b2, w3, b3,
                                   wy, by, wh, bh, wd, bd, ws_hpmean, ws_keys, out);
  k3_Hq<<<32768, 256, 0, stream>>>(Hm, ws_ss, out + O_Hbl, out + O_Hq);
  k4_vq<<<4096, 256, 0, stream>>>(v, ws_ss, out + O_dbl, out + O_vq);
  k5_yq<<<512, 256, 0, stream>>>(y, ws_ss, out + O_yba, out + O_yq);
}